// Round 11
// baseline (280.889 us; speedup 1.0000x reference)
//
#include <hip/hip_runtime.h>
#include <math.h>

#define NEG_SLOPE 0.2f
#define NBUK_MAX 2048   // LDS histogram capacity (buckets of 64 dsts)

// ---------------- K0: fused argmax + embedding-gather + layer-1 transform ----------------
// 16 lanes per node. Argmax over V=128 via float4; emb row broadcast-loads; lane f
// computes column f of h1 = emb_row @ W1; a-dots via 16-lane shfl reduction.
template <int FIN, int FOUT>
__global__ void k_embed_tr(const float* __restrict__ x, const float* __restrict__ emb,
                           const float* __restrict__ W, const float* __restrict__ a_src,
                           const float* __restrict__ a_dst,
                           _Float16* __restrict__ h_t, float* __restrict__ asrc,
                           float* __restrict__ adst, int N, int V) {
    __shared__ float sW[FIN * FOUT];
    __shared__ float sa[FOUT], sd[FOUT];
    for (int i = threadIdx.x; i < FIN * FOUT; i += blockDim.x) sW[i] = W[i];
    if (threadIdx.x < FOUT) { sa[threadIdx.x] = a_src[threadIdx.x]; sd[threadIdx.x] = a_dst[threadIdx.x]; }
    __syncthreads();
    int grp  = (blockIdx.x * blockDim.x + threadIdx.x) >> 4;
    int lane = threadIdx.x & 15;
    if (grp >= N) return;

    const float4* row = (const float4*)(x + (long long)grp * V);
    float bv = -INFINITY;
    int bi = 0x7fffffff;
    int nq = V >> 2;
    for (int q = lane; q < nq; q += 16) {
        float4 v = row[q];
        int base = q << 2;
        if (v.x > bv || (v.x == bv && base     < bi)) { bv = v.x; bi = base;     }
        if (v.y > bv || (v.y == bv && base + 1 < bi)) { bv = v.y; bi = base + 1; }
        if (v.z > bv || (v.z == bv && base + 2 < bi)) { bv = v.z; bi = base + 2; }
        if (v.w > bv || (v.w == bv && base + 3 < bi)) { bv = v.w; bi = base + 3; }
    }
    for (int off = 8; off > 0; off >>= 1) {
        float ov = __shfl_down(bv, off, 16);
        int   oi = __shfl_down(bi, off, 16);
        if (ov > bv || (ov == bv && oi < bi)) { bv = ov; bi = oi; }
    }
    bi = __shfl(bi, 0, 16);

    const float* hr = emb + (long long)bi * FIN;
    float acc = 0.f;
    for (int k = 0; k < FIN; k++) acc += hr[k] * sW[k * FOUT + lane];

    float c1 = acc * sa[lane], c2 = acc * sd[lane];
    for (int off = 8; off > 0; off >>= 1) {
        c1 += __shfl_xor(c1, off, 16);
        c2 += __shfl_xor(c2, off, 16);
    }
    h_t[(long long)grp * 16 + lane] = (_Float16)acc;
    if (lane == 0) { asrc[grp] = c1; adst[grp] = c2; }
}

// ---------------- CSR build: atomic-free counting sort ----------------
template <int B2>
__global__ void __launch_bounds__(1024)
k_histB(const int* __restrict__ edst, int E, int* __restrict__ histT, int NBUK) {
    __shared__ int sh[NBUK_MAX];
    int t = threadIdx.x, b = blockIdx.x;
    for (int k = t; k < NBUK; k += 1024) sh[k] = 0;
    __syncthreads();
    long long ebeg = (long long)b * E / B2, eend = (long long)(b + 1) * E / B2;
    for (long long i = ebeg + t; i < eend; i += 1024)
        atomicAdd(&sh[edst[i] >> 6], 1);
    __syncthreads();
    for (int k = t; k < NBUK; k += 1024) histT[(long long)k * B2 + b] = sh[k];
}

__global__ void k_scan1(const int* __restrict__ vals, int* __restrict__ excl,
                        int* __restrict__ bsums, int M) {
    __shared__ int s[256];
    int i = blockIdx.x * 256 + threadIdx.x;
    int v = (i < M) ? vals[i] : 0;
    s[threadIdx.x] = v;
    __syncthreads();
    for (int off = 1; off < 256; off <<= 1) {
        int a = (threadIdx.x >= (unsigned)off) ? s[threadIdx.x - off] : 0;
        __syncthreads();
        s[threadIdx.x] += a;
        __syncthreads();
    }
    if (i < M) excl[i] = s[threadIdx.x] - v;
    if (threadIdx.x == 255) bsums[blockIdx.x] = s[255];
}

__global__ void k_scan2(int* __restrict__ bsums, int nb) {
    __shared__ int s[2048];
    int i = threadIdx.x;
    int v0 = (i < nb) ? bsums[i] : 0;
    int v1 = (i + 1024 < nb) ? bsums[i + 1024] : 0;
    s[i] = v0;
    s[i + 1024] = v1;
    __syncthreads();
    for (int off = 1; off < 2048; off <<= 1) {
        int a0 = (i >= off) ? s[i - off] : 0;
        int a1 = (i + 1024 >= off) ? s[i + 1024 - off] : 0;
        __syncthreads();
        s[i] += a0;
        s[i + 1024] += a1;
        __syncthreads();
    }
    if (i < nb) bsums[i] = s[i] - v0;
    if (i + 1024 < nb) bsums[i + 1024] = s[i + 1024] - v1;
}

__global__ void k_scan3(const int* __restrict__ excl, const int* __restrict__ bsums,
                        int* __restrict__ soff, int M) {
    int i = blockIdx.x * 256 + threadIdx.x;
    if (i < M) soff[i] = excl[i] + bsums[i >> 8];
}

template <int B2>
__global__ void __launch_bounds__(1024)
k_scatB(const int* __restrict__ esrc, const int* __restrict__ edst, int E,
        const int* __restrict__ soff, int* __restrict__ tmp, int NBUK) {
    __shared__ int cur[NBUK_MAX];
    int t = threadIdx.x, b = blockIdx.x;
    for (int k = t; k < NBUK; k += 1024) cur[k] = soff[(long long)k * B2 + b];
    __syncthreads();
    long long ebeg = (long long)b * E / B2, eend = (long long)(b + 1) * E / B2;
    for (long long i = ebeg + t; i < eend; i += 1024) {
        int d = edst[i];
        int pos = atomicAdd(&cur[d >> 6], 1);
        tmp[pos] = ((d & 63) << 18) | esrc[i];
    }
}

template <int B2>
__global__ void __launch_bounds__(256)
k_binB(const int* __restrict__ soff, const int* __restrict__ tmp,
       int* __restrict__ rowptr, int* __restrict__ csr_src, int N, int NBUK, int E) {
    __shared__ int cnt[64];
    __shared__ int cur[64];
    int t = threadIdx.x, b = blockIdx.x;
    int t0 = soff[(long long)b * B2];
    int t1 = (b + 1 < NBUK) ? soff[(long long)(b + 1) * B2] : E;
    if (t < 64) cnt[t] = 0;
    __syncthreads();
    for (int i = t0 + t; i < t1; i += 256) atomicAdd(&cnt[tmp[i] >> 18], 1);
    __syncthreads();
    if (t < 64) {
        int v = cnt[t];
        int incl = v;
        for (int off = 1; off < 64; off <<= 1) {
            int u = __shfl_up(incl, off, 64);
            if (t >= off) incl += u;
        }
        int base = t0 + incl - v;
        int d = (b << 6) + t;
        if (d < N) rowptr[d] = base;
        cur[t] = base;
        if (d == N - 1) rowptr[N] = E;
    }
    __syncthreads();
    for (int i = t0 + t; i < t1; i += 256) {
        int p = tmp[i];
        int pos = atomicAdd(&cur[p >> 18], 1);
        csr_src[pos] = p & 0x3FFFF;
    }
}

// ---------------- Fused GAT aggregation + bias/ReLU + NEXT-layer transform ----------------
// 16 lanes per dst. Aggregation as in R10 (lane-owned edges, 1 exp/edge, shfl
// broadcast, fp16 row gathers). Epilogue: h_next[f] = sum_k relu(v)_k * Wn[k][f]
// via 16 shfls; a-dots via shfl_xor reduce. X never materialized.
template <int FN>   // next-layer FOUT (16 or 10)
__global__ void k_gat_ft(const int* __restrict__ rowptr, const int* __restrict__ csr_src,
                         const float* __restrict__ asrc, const float* __restrict__ adst,
                         const _Float16* __restrict__ h_t, const float* __restrict__ bias,
                         const float* __restrict__ Wn, const float* __restrict__ an_src,
                         const float* __restrict__ an_dst,
                         _Float16* __restrict__ h_next, float* __restrict__ asrc_n,
                         float* __restrict__ adst_n, int N) {
    __shared__ float sW[16 * FN];
    __shared__ float sa[FN], sd[FN], sb[16];
    for (int i = threadIdx.x; i < 16 * FN; i += blockDim.x) sW[i] = Wn[i];
    if (threadIdx.x < FN) { sa[threadIdx.x] = an_src[threadIdx.x]; sd[threadIdx.x] = an_dst[threadIdx.x]; }
    if (threadIdx.x < 16) sb[threadIdx.x] = bias[threadIdx.x];
    __syncthreads();

    int grp  = (blockIdx.x * blockDim.x + threadIdx.x) >> 4;
    int lane = threadIdx.x & 15;
    if (grp >= N) return;
    int d = grp;
    int r0 = rowptr[d], r1 = rowptr[d + 1];
    float ad = adst[d];

    float e0 = asrc[d] + ad;
    e0 = (e0 >= 0.f) ? e0 : NEG_SLOPE * e0;
    float p0 = __expf(e0);
    float acc  = p0 * (float)h_t[(long long)d * 16 + lane];
    float psum = (lane == 0) ? p0 : 0.f;

    for (int j = r0; j < r1; j += 16) {
        int myj = j + lane;
        bool valid = myj < r1;
        int s = valid ? csr_src[myj] : d;
        float a = asrc[s];
        float e = a + ad;
        e = (e >= 0.f) ? e : NEG_SLOPE * e;
        float p = valid ? __expf(e) : 0.f;
        psum += p;
#pragma unroll
        for (int k = 0; k < 16; k++) {
            float pk = __shfl(p, k, 16);
            int   sk = __shfl(s, k, 16);
            acc += pk * (float)h_t[(long long)sk * 16 + lane];
        }
    }
    for (int off = 8; off > 0; off >>= 1) psum += __shfl_xor(psum, off, 16);

    // this layer's output feature (bias + relu)
    float v = acc / fmaxf(psum, 1e-16f) + sb[lane];
    v = fmaxf(v, 0.f);

    // next-layer transform: lane f accumulates column f
    float acc2 = 0.f;
#pragma unroll
    for (int k = 0; k < 16; k++) {
        float vk = __shfl(v, k, 16);
        if (lane < FN) acc2 += vk * sW[k * FN + lane];
    }
    float c1 = (lane < FN) ? acc2 * sa[lane] : 0.f;
    float c2 = (lane < FN) ? acc2 * sd[lane] : 0.f;
    for (int off = 8; off > 0; off >>= 1) {
        c1 += __shfl_xor(c1, off, 16);
        c2 += __shfl_xor(c2, off, 16);
    }
    h_next[(long long)d * 16 + lane] = (_Float16)((lane < FN) ? acc2 : 0.f);
    if (lane == 0) { asrc_n[d] = c1; adst_n[d] = c2; }
}

// ---------------- final GAT layer (no bias/relu; fp32 out rows of width FOUT) ----------------
template <int FOUT>
__global__ void k_gat_dst(const int* __restrict__ rowptr, const int* __restrict__ csr_src,
                          const float* __restrict__ asrc, const float* __restrict__ adst,
                          const _Float16* __restrict__ h_t, float* __restrict__ out, int N) {
    int grp  = (blockIdx.x * blockDim.x + threadIdx.x) >> 4;
    int lane = threadIdx.x & 15;
    if (grp >= N) return;
    int d = grp;
    int r0 = rowptr[d], r1 = rowptr[d + 1];
    float ad = adst[d];

    float e0 = asrc[d] + ad;
    e0 = (e0 >= 0.f) ? e0 : NEG_SLOPE * e0;
    float p0 = __expf(e0);
    float acc  = p0 * (float)h_t[(long long)d * 16 + lane];
    float psum = (lane == 0) ? p0 : 0.f;

    for (int j = r0; j < r1; j += 16) {
        int myj = j + lane;
        bool valid = myj < r1;
        int s = valid ? csr_src[myj] : d;
        float a = asrc[s];
        float e = a + ad;
        e = (e >= 0.f) ? e : NEG_SLOPE * e;
        float p = valid ? __expf(e) : 0.f;
        psum += p;
#pragma unroll
        for (int k = 0; k < 16; k++) {
            float pk = __shfl(p, k, 16);
            int   sk = __shfl(s, k, 16);
            acc += pk * (float)h_t[(long long)sk * 16 + lane];
        }
    }
    for (int off = 8; off > 0; off >>= 1) psum += __shfl_xor(psum, off, 16);

    if (lane < FOUT)
        out[(long long)d * FOUT + lane] = acc / fmaxf(psum, 1e-16f);
}

// ---------------- pool + softmax ----------------
__global__ void k_pool(const float* __restrict__ h3, const int* __restrict__ batch,
                       const float* __restrict__ b3, float* __restrict__ out, int N, int C) {
    int g = blockIdx.x;
    int lo = 0, hi = N;
    while (lo < hi) { int mid = (lo + hi) >> 1; if (batch[mid] < g) lo = mid + 1; else hi = mid; }
    int start = lo;
    hi = N;
    while (lo < hi) { int mid = (lo + hi) >> 1; if (batch[mid] < g + 1) lo = mid + 1; else hi = mid; }
    int end = lo;

    float sum[16];
    for (int f = 0; f < C; f++) sum[f] = 0.f;
    for (int n = start + threadIdx.x; n < end; n += blockDim.x) {
        const float* r = h3 + (long long)n * C;
        for (int f = 0; f < C; f++) sum[f] += r[f];
    }
    __shared__ float red[256 * 16];
    for (int f = 0; f < C; f++) red[threadIdx.x * 16 + f] = sum[f];
    __syncthreads();
    for (int str = blockDim.x / 2; str > 0; str >>= 1) {
        if ((int)threadIdx.x < str)
            for (int f = 0; f < C; f++) red[threadIdx.x * 16 + f] += red[(threadIdx.x + str) * 16 + f];
        __syncthreads();
    }
    if (threadIdx.x == 0) {
        float cnt = fmaxf((float)(end - start), 1.f);
        float vals[16];
        float mx = -INFINITY;
        for (int f = 0; f < C; f++) { vals[f] = red[f] / cnt + b3[f]; mx = fmaxf(mx, vals[f]); }
        float se = 0.f;
        for (int f = 0; f < C; f++) { vals[f] = __expf(vals[f] - mx); se += vals[f]; }
        for (int f = 0; f < C; f++) out[(long long)g * C + f] = vals[f] / se;
    }
}

extern "C" void kernel_launch(void* const* d_in, const int* in_sizes, int n_in,
                              void* d_out, int out_size, void* d_ws, size_t ws_size,
                              hipStream_t stream) {
    const float* x    = (const float*)d_in[0];
    const int*   eidx = (const int*)d_in[1];
    const int*   batch= (const int*)d_in[2];
    const float* emb  = (const float*)d_in[3];
    const float* W1   = (const float*)d_in[4];
    const float* as1  = (const float*)d_in[5];
    const float* ad1  = (const float*)d_in[6];
    const float* b1   = (const float*)d_in[7];
    const float* W2   = (const float*)d_in[8];
    const float* as2  = (const float*)d_in[9];
    const float* ad2  = (const float*)d_in[10];
    const float* b2   = (const float*)d_in[11];
    const float* W3   = (const float*)d_in[12];
    const float* as3  = (const float*)d_in[13];
    const float* ad3  = (const float*)d_in[14];
    const float* b3   = (const float*)d_in[15];

    const int H = in_sizes[5];          // 16
    const int C = in_sizes[13];         // 10
    const int D = in_sizes[4] / H;      // 50
    const int V = in_sizes[3] / D;      // 128
    const int N = in_sizes[0] / V;      // 100000
    const int E = in_sizes[1] / 2;      // 1600000
    const int G = out_size / C;         // 512
    const int* esrc = eidx;
    const int* edst = eidx + E;
    const int NBUK = (N + 63) >> 6;     // 1563 buckets of 64 dsts
    constexpr int B2 = 256;             // scatter blocks
    const int M = NBUK * B2;            // histT elements (400K)

    char* w = (char*)d_ws;
    auto carve = [&](size_t bytes) {
        char* p = w;
        w += (bytes + 255) & ~(size_t)255;
        return p;
    };
    // persistent
    float*     as_a    = (float*)carve((size_t)N * 4);
    float*     ad_a    = (float*)carve((size_t)N * 4);
    float*     as_b    = (float*)carve((size_t)N * 4);
    float*     ad_b    = (float*)carve((size_t)N * 4);
    int*       rowptr  = (int*)carve((size_t)(N + 1) * 4);
    int*       csr_src = (int*)carve((size_t)E * 4);
    int*       histT   = (int*)carve((size_t)M * 4);
    int*       sexcl   = (int*)carve((size_t)M * 4);
    int*       soff    = (int*)carve((size_t)M * 4);
    int*       bsums   = (int*)carve(2048 * 4);
    _Float16*  hTa     = (_Float16*)carve((size_t)N * 16 * 2);  // 3.2 MB fp16 tables
    _Float16*  hTb     = (_Float16*)carve((size_t)N * 16 * 2);
    // union zone: tmp (build) aliases X0 (final-layer fp32 rows)
    size_t zone_bytes = ((size_t)E * 4 > (size_t)N * C * 4) ? (size_t)E * 4 : (size_t)N * C * 4;
    char*  zone = carve(zone_bytes);
    float* X0  = (float*)zone;
    int*   tmp = (int*)zone;
    (void)ws_size; (void)n_in;

    const int BT = 256;
    dim3 blk(BT);
    int gGat = (N * 16 + BT - 1) / BT;      // 16 lanes per node/dst
    int nb2  = (M + 255) / 256;             // scan blocks over histT (1563 <= 2048)

    // ---- CSR build: counting sort, zero global atomics ----
    k_histB<B2><<<B2, dim3(1024), 0, stream>>>(edst, E, histT, NBUK);
    k_scan1<<<nb2, blk, 0, stream>>>(histT, sexcl, bsums, M);
    k_scan2<<<1, 1024, 0, stream>>>(bsums, nb2);
    k_scan3<<<nb2, blk, 0, stream>>>(sexcl, bsums, soff, M);
    k_scatB<B2><<<B2, dim3(1024), 0, stream>>>(esrc, edst, E, soff, tmp, NBUK);
    k_binB<B2><<<NBUK, blk, 0, stream>>>(soff, tmp, rowptr, csr_src, N, NBUK, E);

    // ---- fused argmax + embedding + layer-1 transform -> hTa, a_a ----
    k_embed_tr<50, 16><<<gGat, blk, 0, stream>>>(x, emb, W1, as1, ad1, hTa, as_a, ad_a, N, V);

    // ---- gat1 (+b1,relu) fused with transform2 -> hTb, a_b ----
    k_gat_ft<16><<<gGat, blk, 0, stream>>>(rowptr, csr_src, as_a, ad_a, hTa, b1,
                                           W2, as2, ad2, hTb, as_b, ad_b, N);

    // ---- gat2 (+b2,relu) fused with transform3 -> hTa, a_a ----
    k_gat_ft<10><<<gGat, blk, 0, stream>>>(rowptr, csr_src, as_b, ad_b, hTb, b2,
                                           W3, as3, ad3, hTa, as_a, ad_a, N);

    // ---- gat3 -> X0 (N x 10 fp32; b3 folded into pool) ----
    k_gat_dst<10><<<gGat, blk, 0, stream>>>(rowptr, csr_src, as_a, ad_a, hTa, X0, N);

    // ---- pool + softmax ----
    k_pool<<<G, blk, 0, stream>>>(X0, batch, b3, (float*)d_out, N, C);
}

// Round 12
// 274.060 us; speedup vs baseline: 1.0249x; 1.0249x over previous
//
#include <hip/hip_runtime.h>
#include <math.h>

#define NEG_SLOPE 0.2f
#define NBUK_MAX 2048   // LDS histogram capacity (buckets of 64 dsts)

// ---------------- K0a: argmax over V features -> idx ----------------
__global__ void k_argmax(const float* __restrict__ x, int* __restrict__ idx, int N, int V) {
    int node = (blockIdx.x * blockDim.x + threadIdx.x) >> 5;   // 32 lanes per node
    int lane = threadIdx.x & 31;
    if (node >= N) return;
    const float4* row = (const float4*)(x + (long long)node * V);
    float bv = -INFINITY;
    int bi = 0x7fffffff;
    int nq = V >> 2;
    for (int q = lane; q < nq; q += 32) {
        float4 v = row[q];
        int base = q << 2;
        if (v.x > bv || (v.x == bv && base     < bi)) { bv = v.x; bi = base;     }
        if (v.y > bv || (v.y == bv && base + 1 < bi)) { bv = v.y; bi = base + 1; }
        if (v.z > bv || (v.z == bv && base + 2 < bi)) { bv = v.z; bi = base + 2; }
        if (v.w > bv || (v.w == bv && base + 3 < bi)) { bv = v.w; bi = base + 3; }
    }
    for (int off = 16; off > 0; off >>= 1) {
        float ov = __shfl_down(bv, off, 32);
        int   oi = __shfl_down(bi, off, 32);
        if (ov > bv || (ov == bv && oi < bi)) { bv = ov; bi = oi; }
    }
    if (lane == 0) idx[node] = bi;
}

// ---------------- K1: dense transform + attention scalars ----------------
// Output h_t rows in fp16, padded to 16 halves (32 B) -> 3.2 MB table fits per-XCD L2.
template <int FIN, int FOUT, bool GATHER>
__global__ void k_transform(const float* __restrict__ h_in, const int* __restrict__ idx,
                            const float* __restrict__ W,
                            const float* __restrict__ a_src, const float* __restrict__ a_dst,
                            _Float16* __restrict__ h_t, float* __restrict__ asrc,
                            float* __restrict__ adst, int N) {
    __shared__ float sW[FIN * FOUT];
    __shared__ float sa[FOUT], sd[FOUT];
    for (int i = threadIdx.x; i < FIN * FOUT; i += blockDim.x) sW[i] = W[i];
    if (threadIdx.x < FOUT) { sa[threadIdx.x] = a_src[threadIdx.x]; sd[threadIdx.x] = a_dst[threadIdx.x]; }
    __syncthreads();
    int n = blockIdx.x * blockDim.x + threadIdx.x;
    if (n >= N) return;
    float acc[FOUT];
#pragma unroll
    for (int f = 0; f < FOUT; f++) acc[f] = 0.f;
    const float* hr = GATHER ? (h_in + (long long)idx[n] * FIN)
                             : (h_in + (long long)n * FIN);
    for (int k = 0; k < FIN; k++) {
        float v = hr[k];
#pragma unroll
        for (int f = 0; f < FOUT; f++) acc[f] += v * sW[k * FOUT + f];
    }
    float s1 = 0.f, s2 = 0.f;
    _Float16 hh[16];
#pragma unroll
    for (int f = 0; f < 16; f++) hh[f] = (_Float16)0.f;
#pragma unroll
    for (int f = 0; f < FOUT; f++) {
        hh[f] = (_Float16)acc[f];
        s1 += acc[f] * sa[f];
        s2 += acc[f] * sd[f];
    }
    uint4* dst = (uint4*)(h_t + (long long)n * 16);
    dst[0] = ((uint4*)hh)[0];
    dst[1] = ((uint4*)hh)[1];
    asrc[n] = s1;
    adst[n] = s2;
}

// ---------------- CSR build: atomic-free counting sort ----------------
template <int B2>
__global__ void __launch_bounds__(1024)
k_histB(const int* __restrict__ edst, int E, int* __restrict__ histT, int NBUK) {
    __shared__ int sh[NBUK_MAX];
    int t = threadIdx.x, b = blockIdx.x;
    for (int k = t; k < NBUK; k += 1024) sh[k] = 0;
    __syncthreads();
    long long ebeg = (long long)b * E / B2, eend = (long long)(b + 1) * E / B2;
    for (long long i = ebeg + t; i < eend; i += 1024)
        atomicAdd(&sh[edst[i] >> 6], 1);
    __syncthreads();
    for (int k = t; k < NBUK; k += 1024) histT[(long long)k * B2 + b] = sh[k];
}

__global__ void k_scan1(const int* __restrict__ vals, int* __restrict__ excl,
                        int* __restrict__ bsums, int M) {
    __shared__ int s[256];
    int i = blockIdx.x * 256 + threadIdx.x;
    int v = (i < M) ? vals[i] : 0;
    s[threadIdx.x] = v;
    __syncthreads();
    for (int off = 1; off < 256; off <<= 1) {
        int a = (threadIdx.x >= (unsigned)off) ? s[threadIdx.x - off] : 0;
        __syncthreads();
        s[threadIdx.x] += a;
        __syncthreads();
    }
    if (i < M) excl[i] = s[threadIdx.x] - v;
    if (threadIdx.x == 255) bsums[blockIdx.x] = s[255];
}

__global__ void k_scan2(int* __restrict__ bsums, int nb) {
    __shared__ int s[2048];
    int i = threadIdx.x;
    int v0 = (i < nb) ? bsums[i] : 0;
    int v1 = (i + 1024 < nb) ? bsums[i + 1024] : 0;
    s[i] = v0;
    s[i + 1024] = v1;
    __syncthreads();
    for (int off = 1; off < 2048; off <<= 1) {
        int a0 = (i >= off) ? s[i - off] : 0;
        int a1 = (i + 1024 >= off) ? s[i + 1024 - off] : 0;
        __syncthreads();
        s[i] += a0;
        s[i + 1024] += a1;
        __syncthreads();
    }
    if (i < nb) bsums[i] = s[i] - v0;
    if (i + 1024 < nb) bsums[i + 1024] = s[i + 1024] - v1;
}

// exact-slot scatter; LDS cursors only. soff folded in: cur[k]=sexcl[k*B2+b]+bsums[k]
template <int B2>
__global__ void __launch_bounds__(1024)
k_scatB(const int* __restrict__ esrc, const int* __restrict__ edst, int E,
        const int* __restrict__ sexcl, const int* __restrict__ bsums,
        int* __restrict__ tmp, int NBUK) {
    __shared__ int cur[NBUK_MAX];
    int t = threadIdx.x, b = blockIdx.x;
    for (int k = t; k < NBUK; k += 1024)
        cur[k] = sexcl[(long long)k * B2 + b] + bsums[k];
    __syncthreads();
    long long ebeg = (long long)b * E / B2, eend = (long long)(b + 1) * E / B2;
    for (long long i = ebeg + t; i < eend; i += 1024) {
        int d = edst[i];
        int pos = atomicAdd(&cur[d >> 6], 1);
        tmp[pos] = ((d & 63) << 18) | esrc[i];
    }
}

template <int B2>
__global__ void __launch_bounds__(256)
k_binB(const int* __restrict__ sexcl, const int* __restrict__ bsums,
       const int* __restrict__ tmp,
       int* __restrict__ rowptr, int* __restrict__ csr_src, int N, int NBUK, int E) {
    __shared__ int cnt[64];
    __shared__ int cur[64];
    int t = threadIdx.x, b = blockIdx.x;
    int t0 = sexcl[(long long)b * B2] + bsums[b];
    int t1 = (b + 1 < NBUK) ? (sexcl[(long long)(b + 1) * B2] + bsums[b + 1]) : E;
    if (t < 64) cnt[t] = 0;
    __syncthreads();
    for (int i = t0 + t; i < t1; i += 256) atomicAdd(&cnt[tmp[i] >> 18], 1);
    __syncthreads();
    if (t < 64) {
        int v = cnt[t];
        int incl = v;
        for (int off = 1; off < 64; off <<= 1) {
            int u = __shfl_up(incl, off, 64);
            if (t >= off) incl += u;
        }
        int base = t0 + incl - v;
        int d = (b << 6) + t;
        if (d < N) rowptr[d] = base;
        cur[t] = base;
        if (d == N - 1) rowptr[N] = E;
    }
    __syncthreads();
    for (int i = t0 + t; i < t1; i += 256) {
        int p = tmp[i];
        int pos = atomicAdd(&cur[p >> 18], 1);
        csr_src[pos] = p & 0x3FFFF;
    }
}

// ---------------- Fused per-dst GAT aggregation (software-pipelined) ----------------
// 16 lanes per dst; lane owns one of 16 edges/iter. Next iteration's csr_src +
// asrc gather issue BEFORE the 16-step shfl/FMA phase -> the two chained gather
// latencies overlap the compute phase.
template <int FOUT, bool BIAS, bool RELU>
__global__ void k_gat_dst(const int* __restrict__ rowptr, const int* __restrict__ csr_src,
                          const float* __restrict__ asrc, const float* __restrict__ adst,
                          const _Float16* __restrict__ h_t, const float* __restrict__ b,
                          float* __restrict__ out, int N) {
    int grp  = (blockIdx.x * blockDim.x + threadIdx.x) >> 4;
    int lane = threadIdx.x & 15;
    if (grp >= N) return;
    int d = grp;
    int r0 = rowptr[d], r1 = rowptr[d + 1];
    float ad = adst[d];
    constexpr bool FULL = (FOUT == 16);
    const bool active = FULL || lane < FOUT;

    // self-loop
    float e0 = asrc[d] + ad;
    e0 = (e0 >= 0.f) ? e0 : NEG_SLOPE * e0;
    float p0 = __expf(e0);
    float acc  = p0 * (float)h_t[(long long)d * 16 + lane];   // padded rows: all lanes safe
    float psum = (lane == 0) ? p0 : 0.f;

    int j = r0;
    if (j < r1) {
        int myj = j + lane;
        bool valid = myj < r1;
        int s = valid ? csr_src[myj] : d;
        float a = asrc[s];
        while (true) {
            int jn = j + 16;
            int s2 = d; float a2 = 0.f; bool validn = false;
            if (jn < r1) {                       // prefetch next 16 edges
                int myjn = jn + lane;
                validn = myjn < r1;
                s2 = validn ? csr_src[myjn] : d;
                a2 = asrc[s2];
            }
            float e = a + ad;
            e = (e >= 0.f) ? e : NEG_SLOPE * e;
            float p = valid ? __expf(e) : 0.f;
            psum += p;
#pragma unroll
            for (int k = 0; k < 16; k++) {
                float pk = __shfl(p, k, 16);
                int   sk = __shfl(s, k, 16);
                acc += pk * (float)h_t[(long long)sk * 16 + lane];
            }
            if (jn >= r1) break;
            j = jn; s = s2; a = a2; valid = validn;
        }
    }
    for (int off = 8; off > 0; off >>= 1) psum += __shfl_xor(psum, off, 16);

    if (active) {
        float v = acc / fmaxf(psum, 1e-16f);
        if (BIAS) v += b[lane];
        if (RELU) v = fmaxf(v, 0.f);
        out[(long long)d * FOUT + lane] = v;
    }
}

// ---------------- K6: pool + softmax ----------------
__global__ void k_pool(const float* __restrict__ h3, const int* __restrict__ batch,
                       const float* __restrict__ b3, float* __restrict__ out, int N, int C) {
    int g = blockIdx.x;
    int lo = 0, hi = N;
    while (lo < hi) { int mid = (lo + hi) >> 1; if (batch[mid] < g) lo = mid + 1; else hi = mid; }
    int start = lo;
    hi = N;
    while (lo < hi) { int mid = (lo + hi) >> 1; if (batch[mid] < g + 1) lo = mid + 1; else hi = mid; }
    int end = lo;

    float sum[16];
    for (int f = 0; f < C; f++) sum[f] = 0.f;
    for (int n = start + threadIdx.x; n < end; n += blockDim.x) {
        const float* r = h3 + (long long)n * C;
        for (int f = 0; f < C; f++) sum[f] += r[f];
    }
    __shared__ float red[256 * 16];
    for (int f = 0; f < C; f++) red[threadIdx.x * 16 + f] = sum[f];
    __syncthreads();
    for (int str = blockDim.x / 2; str > 0; str >>= 1) {
        if ((int)threadIdx.x < str)
            for (int f = 0; f < C; f++) red[threadIdx.x * 16 + f] += red[(threadIdx.x + str) * 16 + f];
        __syncthreads();
    }
    if (threadIdx.x == 0) {
        float cnt = fmaxf((float)(end - start), 1.f);
        float vals[16];
        float mx = -INFINITY;
        for (int f = 0; f < C; f++) { vals[f] = red[f] / cnt + b3[f]; mx = fmaxf(mx, vals[f]); }
        float se = 0.f;
        for (int f = 0; f < C; f++) { vals[f] = __expf(vals[f] - mx); se += vals[f]; }
        for (int f = 0; f < C; f++) out[(long long)g * C + f] = vals[f] / se;
    }
}

extern "C" void kernel_launch(void* const* d_in, const int* in_sizes, int n_in,
                              void* d_out, int out_size, void* d_ws, size_t ws_size,
                              hipStream_t stream) {
    const float* x    = (const float*)d_in[0];
    const int*   eidx = (const int*)d_in[1];
    const int*   batch= (const int*)d_in[2];
    const float* emb  = (const float*)d_in[3];
    const float* W1   = (const float*)d_in[4];
    const float* as1  = (const float*)d_in[5];
    const float* ad1  = (const float*)d_in[6];
    const float* b1   = (const float*)d_in[7];
    const float* W2   = (const float*)d_in[8];
    const float* as2  = (const float*)d_in[9];
    const float* ad2  = (const float*)d_in[10];
    const float* b2   = (const float*)d_in[11];
    const float* W3   = (const float*)d_in[12];
    const float* as3  = (const float*)d_in[13];
    const float* ad3  = (const float*)d_in[14];
    const float* b3   = (const float*)d_in[15];

    const int H = in_sizes[5];          // 16
    const int C = in_sizes[13];         // 10
    const int D = in_sizes[4] / H;      // 50
    const int V = in_sizes[3] / D;      // 128
    const int N = in_sizes[0] / V;      // 100000
    const int E = in_sizes[1] / 2;      // 1600000
    const int G = out_size / C;         // 512
    const int* esrc = eidx;
    const int* edst = eidx + E;
    const int NBUK = (N + 63) >> 6;     // 1563 buckets of 64 dsts
    constexpr int B2 = 256;             // scatter blocks
    const int M = NBUK * B2;            // histT elements (400K)

    char* w = (char*)d_ws;
    auto carve = [&](size_t bytes) {
        char* p = w;
        w += (bytes + 255) & ~(size_t)255;
        return p;
    };
    // persistent
    float*     asrc    = (float*)carve((size_t)N * 4);
    float*     adst    = (float*)carve((size_t)N * 4);
    int*       idx     = (int*)carve((size_t)N * 4);
    int*       rowptr  = (int*)carve((size_t)(N + 1) * 4);
    int*       csr_src = (int*)carve((size_t)E * 4);
    int*       histT   = (int*)carve((size_t)M * 4);
    int*       sexcl   = (int*)carve((size_t)M * 4);
    int*       bsums   = (int*)carve(2048 * 4);
    _Float16*  hT      = (_Float16*)carve((size_t)N * 16 * 2);  // 3.2 MB fp16 gather table
    // union zone: tmp (build) aliases X0/X1 (compute)
    char*  zone = w;
    float* X0 = (float*)zone;
    float* X1 = (float*)(zone + (((size_t)N * H * 4 + 255) & ~(size_t)255));
    int*   tmp = (int*)zone;            // E ints = 6.4 MB <= X0+X1 (12.8 MB)
    (void)ws_size; (void)n_in;

    const int BT = 256;
    dim3 blk(BT);
    int gN   = (N + BT - 1) / BT;
    int gArg = (N * 32 + BT - 1) / BT;      // 32 lanes per node
    int gGat = (N * 16 + BT - 1) / BT;      // 16 lanes per dst
    int nb2  = (M + 255) / 256;             // scan blocks over histT (1563 <= 2048)

    // ---- CSR build: counting sort, zero global atomics ----
    k_histB<B2><<<B2, dim3(1024), 0, stream>>>(edst, E, histT, NBUK);
    k_scan1<<<nb2, blk, 0, stream>>>(histT, sexcl, bsums, M);
    k_scan2<<<1, 1024, 0, stream>>>(bsums, nb2);
    k_scatB<B2><<<B2, dim3(1024), 0, stream>>>(esrc, edst, E, sexcl, bsums, tmp, NBUK);
    k_binB<B2><<<NBUK, blk, 0, stream>>>(sexcl, bsums, tmp, rowptr, csr_src, N, NBUK, E);

    // ---- argmax -> idx ----
    k_argmax<<<gArg, blk, 0, stream>>>(x, idx, N, V);

    // ---- layer 1: 50 -> 16 (gathered from L1-resident emb), +b1, relu ----
    k_transform<50, 16, true><<<gN, blk, 0, stream>>>(emb, idx, W1, as1, ad1, hT, asrc, adst, N);
    k_gat_dst<16, true, true><<<gGat, blk, 0, stream>>>(rowptr, csr_src, asrc, adst, hT, b1, X0, N);

    // ---- layer 2: 16 -> 16, +b2, relu ----
    k_transform<16, 16, false><<<gN, blk, 0, stream>>>(X0, nullptr, W2, as2, ad2, hT, asrc, adst, N);
    k_gat_dst<16, true, true><<<gGat, blk, 0, stream>>>(rowptr, csr_src, asrc, adst, hT, b2, X1, N);

    // ---- layer 3: 16 -> 10, bias folded into pool ----
    k_transform<16, 10, false><<<gN, blk, 0, stream>>>(X1, nullptr, W3, as3, ad3, hT, asrc, adst, N);
    k_gat_dst<10, false, false><<<gGat, blk, 0, stream>>>(rowptr, csr_src, asrc, adst, hT, nullptr, X0, N);

    // ---- pool + softmax ----
    k_pool<<<G, blk, 0, stream>>>(X0, batch, b3, (float*)d_out, N, C);
}